// Round 13
// baseline (2987.844 us; speedup 1.0000x reference)
//
#include <hip/hip_runtime.h>

// LearnPermutations: K=256 independent 256x256 Sinkhorn normalizations.
// R13: pair-split cooperative kernel (2x512-thread blocks per matrix, L2
// partial-vector exchange with release/acquire handshake), now with an
// ERROR-CHECKED cooperative launch: on any launch failure we run the proven
// single-block kernel (R10/R11, 82.9 us) instead. Both paths produce
// identical output, so the dispatch choice stays deterministic per call.

#define KMAT 256
#define GBUF_FLOATS (512 * 512)
#define GBUF_BYTES (GBUF_FLOATS * 4)
#define FLAGS_BYTES (512 * 4)

typedef float f2 __attribute__((ext_vector_type(2)));
typedef unsigned uint2_ev __attribute__((ext_vector_type(2)));

__device__ __forceinline__ float fast_exp2(float x) {
#if __has_builtin(__builtin_amdgcn_exp2f)
  return __builtin_amdgcn_exp2f(x);
#else
  return exp2f(x);
#endif
}

__device__ __forceinline__ float fast_log2(float x) {
#if __has_builtin(__builtin_amdgcn_logf)
  return __builtin_amdgcn_logf(x);
#else
  return __log2f(x);
#endif
}

__device__ __forceinline__ float fast_rcp(float x) {
#if __has_builtin(__builtin_amdgcn_rcpf)
  return __builtin_amdgcn_rcpf(x);
#else
  return 1.0f / x;
#endif
}

__device__ __forceinline__ f2 f2fma(f2 a, f2 b, f2 c) {
#if __has_builtin(__builtin_elementwise_fma)
  return __builtin_elementwise_fma(a, b, c);
#else
  f2 r; r[0] = fmaf(a[0], b[0], c[0]); r[1] = fmaf(a[1], b[1], c[1]); return r;
#endif
}

template <int CTRL>
__device__ __forceinline__ float dpp_movf(float x) {
  return __int_as_float(
      __builtin_amdgcn_update_dpp(0, __float_as_int(x), CTRL, 0xf, 0xf, true));
}

__device__ __forceinline__ uint2_ev pl16_swap(unsigned a, unsigned b) {
  return __builtin_amdgcn_permlane16_swap(a, b, false, false);
}

// 32-lane half-group reductions (verified construction, R1-R12).
__device__ __forceinline__ float hgroup_max(float x) {
  x = fmaxf(x, dpp_movf<0x121>(x));
  x = fmaxf(x, dpp_movf<0x122>(x));
  x = fmaxf(x, dpp_movf<0x124>(x));
  x = fmaxf(x, dpp_movf<0x128>(x));
  uint2_ev r = pl16_swap(__float_as_uint(x), __float_as_uint(x));
  return fmaxf(__uint_as_float(r[0]), __uint_as_float(r[1]));
}

__device__ __forceinline__ float hgroup_sum(float x) {
  x += dpp_movf<0x121>(x);
  x += dpp_movf<0x122>(x);
  x += dpp_movf<0x124>(x);
  x += dpp_movf<0x128>(x);
  uint2_ev r = pl16_swap(__float_as_uint(x), __float_as_uint(x));
  return __uint_as_float(r[0]) + __uint_as_float(r[1]);
}

// Combine lane l with lane l^32 (verified R1-R12 construction).
__device__ __forceinline__ float x32_sum(float x) {
#if __has_builtin(__builtin_amdgcn_permlane32_swap)
  uint2_ev r = __builtin_amdgcn_permlane32_swap(
      (unsigned)__float_as_int(x), (unsigned)__float_as_int(x), false, false);
  return __int_as_float((int)r[0]) + __int_as_float((int)r[1]);
#else
  return x + __shfl_xor(x, 32, 64);
#endif
}

// Gumbel noise + temperature scaling, output in log2 domain.
__device__ __forceinline__ float gumbel_la(float p, float uv, float scale) {
  float lnu = fast_log2(uv + 1e-20f) * 0.69314718056f;
  float g = fast_log2(1e-20f - lnu) * (-0.0069314718056f);
  return (p + g) * scale;
}

__device__ __forceinline__ void schedule_params(const int* itp, int* n_iters,
                                                float* scale) {
  double frac = (double)itp[0] * 1e-5;
  frac = frac < 0.0 ? 0.0 : (frac > 1.0 ? 1.0 : frac);
  *n_iters = (int)(20.0 + frac * 130.0);
  const float tauf = (float)exp2((-3.0 - 4.0 * frac) * 3.3219280948873623);
  *scale = (float)(1.4426950408889634 / (double)tauf);
}

// ============================ pair-split kernel ============================
__global__ __launch_bounds__(512)
__attribute__((amdgpu_waves_per_eu(4, 4)))
void lp_pair_kernel(const float* __restrict__ plw,
                    const float* __restrict__ uin,
                    const int* __restrict__ itp, float* __restrict__ out,
                    float* __restrict__ gbuf, int* __restrict__ flags) {
  const int b = blockIdx.x;
  const int m = b >> 1;
  const int side = b & 1;
  const int t = threadIdx.x;
  const int bc = t & 31;
  const int rg = t >> 5;
  const int wv = t >> 6;
  const int lane = t & 63;

  __shared__ f2 pw[8][132];
  __shared__ f2 colvp[132];
  float* pwF = (float*)pw;
  float* colvF = (float*)colvp;

  const int ts = t >> 1;
  const int tq = t & 1;

  int n_iters; float scale;
  schedule_params(itp, &n_iters, &scale);

  f2 la[8][4];
  float u[8];

  const int rowbase = (side << 7) + (rg << 3);
  const float4* p4 = (const float4*)plw + m * 16384;
  const float4* u4 = (const float4*)uin + m * 16384;
#pragma unroll
  for (int i = 0; i < 8; ++i) {
    const int ridx = (rowbase + i) * 64 + (bc << 1);
    float4 p0 = p4[ridx];
    float4 p1 = p4[ridx + 1];
    float4 v0 = u4[ridx];
    float4 v1 = u4[ridx + 1];
    la[i][0] = f2{gumbel_la(p0.x, v0.x, scale), gumbel_la(p0.y, v0.y, scale)};
    la[i][1] = f2{gumbel_la(p0.z, v0.z, scale), gumbel_la(p0.w, v0.w, scale)};
    la[i][2] = f2{gumbel_la(p1.x, v1.x, scale), gumbel_la(p1.y, v1.y, scale)};
    la[i][3] = f2{gumbel_la(p1.z, v1.z, scale), gumbel_la(p1.w, v1.w, scale)};
  }

  f2 cs[4];
#pragma unroll
  for (int i = 0; i < 8; ++i) {
    float mx = fmaxf(la[i][0][0], la[i][0][1]);
#pragma unroll
    for (int p = 1; p < 4; ++p) mx = fmaxf(mx, fmaxf(la[i][p][0], la[i][p][1]));
    mx = hgroup_max(mx);
    float s = 0.f;
#pragma unroll
    for (int p = 0; p < 4; ++p) {
      la[i][p] = f2{fast_exp2(la[i][p][0] - mx), fast_exp2(la[i][p][1] - mx)};
      s += la[i][p][0] + la[i][p][1];
    }
    s = hgroup_sum(s);
    u[i] = fast_rcp(s);
    const f2 ub = f2{u[i], u[i]};
    if (i == 0) {
#pragma unroll
      for (int p = 0; p < 4; ++p) cs[p] = la[i][p] * ub;
    } else {
#pragma unroll
      for (int p = 0; p < 4; ++p) cs[p] = f2fma(la[i][p], ub, cs[p]);
    }
  }

  const int myflag = (m << 1) + side;
  const int pfflag = (m << 1) + (side ^ 1);

  for (int it = 1; it <= n_iters; ++it) {
    if (it > 1) {
      f2 v2[4];
#pragma unroll
      for (int p = 0; p < 4; ++p) v2[p] = colvp[32 * p + bc];
#pragma unroll
      for (int i = 0; i < 8; ++i) {
        f2 a01 = la[i][0] * v2[0];
        a01 = f2fma(la[i][1], v2[1], a01);
        f2 a23 = la[i][2] * v2[2];
        a23 = f2fma(la[i][3], v2[3], a23);
        f2 acc = a01 + a23;
        u[i] = fast_rcp(hgroup_sum(acc[0] + acc[1]));
      }
      {
        const f2 ub0 = f2{u[0], u[0]};
#pragma unroll
        for (int p = 0; p < 4; ++p) cs[p] = la[0][p] * ub0;
      }
#pragma unroll
      for (int i = 1; i < 8; ++i) {
        const f2 ub = f2{u[i], u[i]};
#pragma unroll
        for (int p = 0; p < 4; ++p) cs[p] = f2fma(la[i][p], ub, cs[p]);
      }
    }

#pragma unroll
    for (int p = 0; p < 4; ++p)
      cs[p] = f2{x32_sum(cs[p][0]), x32_sum(cs[p][1])};
    if (lane < 32) {
#pragma unroll
      for (int p = 0; p < 4; ++p) pw[wv][32 * p + bc] = cs[p];
    }
    __syncthreads();

    float v = pwF[tq * 264 + ts];
#pragma unroll
    for (int w = 1; w < 4; ++w) v += pwF[(tq + 2 * w) * 264 + ts];
    v += dpp_movf<0xB1>(v);

    const int par = (it & 1) << 8;
    if (tq == 0) gbuf[(myflag << 9) + par + ts] = v;
    __threadfence();
    __syncthreads();
    if (t == 0)
      __hip_atomic_store(&flags[myflag], it, __ATOMIC_RELEASE,
                         __HIP_MEMORY_SCOPE_AGENT);
    if (tq == 0) {
      while (__hip_atomic_load(&flags[pfflag], __ATOMIC_ACQUIRE,
                               __HIP_MEMORY_SCOPE_AGENT) < it) {
        __builtin_amdgcn_s_sleep(2);
      }
      const float o = __hip_atomic_load(&gbuf[(pfflag << 9) + par + ts],
                                        __ATOMIC_RELAXED,
                                        __HIP_MEMORY_SCOPE_AGENT);
      colvF[ts] = fast_rcp(v + o);
    }
    __syncthreads();
  }

  f2 v2[4];
#pragma unroll
  for (int p = 0; p < 4; ++p) v2[p] = colvp[32 * p + bc];

  float4* o4 = (float4*)out + m * 16384;
#pragma unroll
  for (int i = 0; i < 8; ++i) {
    const int ridx = (rowbase + i) * 64 + (bc << 1);
    const f2 ub = f2{u[i], u[i]};
    f2 r0 = (la[i][0] * ub) * v2[0];
    f2 r1 = (la[i][1] * ub) * v2[1];
    f2 r2 = (la[i][2] * ub) * v2[2];
    f2 r3 = (la[i][3] * ub) * v2[3];
    float4 a, bb;
    a.x = r0[0]; a.y = r0[1]; a.z = r1[0]; a.w = r1[1];
    bb.x = r2[0]; bb.y = r2[1]; bb.z = r3[0]; bb.w = r3[1];
    o4[ridx] = a;
    o4[ridx + 1] = bb;
  }
}

// ===================== fallback: proven single-block (R10/R11) ==============
__global__ __launch_bounds__(1024)
__attribute__((amdgpu_waves_per_eu(4, 4)))
void lp_sinkhorn_kernel(
    const float* __restrict__ plw, const float* __restrict__ uin,
    const int* __restrict__ itp, float* __restrict__ out) {
  const int k = blockIdx.x;
  const int t = threadIdx.x;
  const int br = t >> 5;
  const int bc = t & 31;
  const int wv = t >> 6;
  const int lane = t & 63;

  __shared__ f2 pw[16][132];
  __shared__ f2 colvp[132];
  float* pwF = (float*)pw;
  float* colvF = (float*)colvp;

  const int ts = t >> 2;
  const int tq = t & 3;

  int n_iters; float scale;
  schedule_params(itp, &n_iters, &scale);

  f2 la[8][4];
  float u[8];

  const float4* p4 = (const float4*)plw + k * 16384;
  const float4* u4 = (const float4*)uin + k * 16384;
#pragma unroll
  for (int i = 0; i < 8; ++i) {
    const int ridx = ((br << 3) + i) * 64 + (bc << 1);
    float4 p0 = p4[ridx];
    float4 p1 = p4[ridx + 1];
    float4 v0 = u4[ridx];
    float4 v1 = u4[ridx + 1];
    la[i][0] = f2{gumbel_la(p0.x, v0.x, scale), gumbel_la(p0.y, v0.y, scale)};
    la[i][1] = f2{gumbel_la(p0.z, v0.z, scale), gumbel_la(p0.w, v0.w, scale)};
    la[i][2] = f2{gumbel_la(p1.x, v1.x, scale), gumbel_la(p1.y, v1.y, scale)};
    la[i][3] = f2{gumbel_la(p1.z, v1.z, scale), gumbel_la(p1.w, v1.w, scale)};
  }

  f2 cs[4];
#pragma unroll
  for (int i = 0; i < 8; ++i) {
    float mx = fmaxf(la[i][0][0], la[i][0][1]);
#pragma unroll
    for (int p = 1; p < 4; ++p) mx = fmaxf(mx, fmaxf(la[i][p][0], la[i][p][1]));
    mx = hgroup_max(mx);
    float s = 0.f;
#pragma unroll
    for (int p = 0; p < 4; ++p) {
      la[i][p] = f2{fast_exp2(la[i][p][0] - mx), fast_exp2(la[i][p][1] - mx)};
      s += la[i][p][0] + la[i][p][1];
    }
    s = hgroup_sum(s);
    u[i] = fast_rcp(s);
    const f2 ub = f2{u[i], u[i]};
    if (i == 0) {
#pragma unroll
      for (int p = 0; p < 4; ++p) cs[p] = la[i][p] * ub;
    } else {
#pragma unroll
      for (int p = 0; p < 4; ++p) cs[p] = f2fma(la[i][p], ub, cs[p]);
    }
  }

  for (int it = 1; it <= n_iters; ++it) {
    if (it > 1) {
      f2 v2[4];
#pragma unroll
      for (int p = 0; p < 4; ++p) v2[p] = colvp[32 * p + bc];
#pragma unroll
      for (int i = 0; i < 8; ++i) {
        f2 a01 = la[i][0] * v2[0];
        a01 = f2fma(la[i][1], v2[1], a01);
        f2 a23 = la[i][2] * v2[2];
        a23 = f2fma(la[i][3], v2[3], a23);
        f2 acc = a01 + a23;
        u[i] = fast_rcp(hgroup_sum(acc[0] + acc[1]));
      }
      {
        const f2 ub0 = f2{u[0], u[0]};
#pragma unroll
        for (int p = 0; p < 4; ++p) cs[p] = la[0][p] * ub0;
      }
#pragma unroll
      for (int i = 1; i < 8; ++i) {
        const f2 ub = f2{u[i], u[i]};
#pragma unroll
        for (int p = 0; p < 4; ++p) cs[p] = f2fma(la[i][p], ub, cs[p]);
      }
    }
#pragma unroll
    for (int p = 0; p < 4; ++p)
      cs[p] = f2{x32_sum(cs[p][0]), x32_sum(cs[p][1])};
    if (lane < 32) {
#pragma unroll
      for (int p = 0; p < 4; ++p) pw[wv][32 * p + bc] = cs[p];
    }
    __syncthreads();
    {
      float v = pwF[tq * 264 + ts];
#pragma unroll
      for (int w = 1; w < 4; ++w) v += pwF[(4 * w + tq) * 264 + ts];
      v += dpp_movf<0xB1>(v);
      v += dpp_movf<0x4E>(v);
      if (tq == 0) colvF[ts] = fast_rcp(v);
    }
    __syncthreads();
  }

  f2 v2[4];
#pragma unroll
  for (int p = 0; p < 4; ++p) v2[p] = colvp[32 * p + bc];

  float4* o4 = (float4*)out + k * 16384;
#pragma unroll
  for (int i = 0; i < 8; ++i) {
    const int ridx = ((br << 3) + i) * 64 + (bc << 1);
    const f2 ub = f2{u[i], u[i]};
    f2 r0 = (la[i][0] * ub) * v2[0];
    f2 r1 = (la[i][1] * ub) * v2[1];
    f2 r2 = (la[i][2] * ub) * v2[2];
    f2 r3 = (la[i][3] * ub) * v2[3];
    float4 a, bb;
    a.x = r0[0]; a.y = r0[1]; a.z = r1[0]; a.w = r1[1];
    bb.x = r2[0]; bb.y = r2[1]; bb.z = r3[0]; bb.w = r3[1];
    o4[ridx] = a;
    o4[ridx + 1] = bb;
  }
}

extern "C" void kernel_launch(void* const* d_in, const int* in_sizes, int n_in,
                              void* d_out, int out_size, void* d_ws,
                              size_t ws_size, hipStream_t stream) {
  const float* plw = (const float*)d_in[0];
  const float* u = (const float*)d_in[1];
  const int* iters = (const int*)d_in[2];
  float* out = (float*)d_out;
  (void)in_sizes; (void)n_in; (void)out_size;

  bool launched = false;
  const size_t need = (size_t)GBUF_BYTES + FLAGS_BYTES;
  if (ws_size >= need) {
    float* gbuf = (float*)d_ws;
    int* flags = (int*)((char*)d_ws + GBUF_BYTES);
    if (hipMemsetAsync(flags, 0, FLAGS_BYTES, stream) == hipSuccess) {
      void* args[6];
      args[0] = (void*)&plw;
      args[1] = (void*)&u;
      args[2] = (void*)&iters;
      args[3] = (void*)&out;
      args[4] = (void*)&gbuf;
      args[5] = (void*)&flags;
      hipError_t e = hipLaunchCooperativeKernel((void*)lp_pair_kernel,
                                                dim3(2 * KMAT), dim3(512),
                                                args, 0, stream);
      launched = (e == hipSuccess);
    }
  }
  if (!launched) {
    lp_sinkhorn_kernel<<<dim3(KMAT), dim3(1024), 0, stream>>>(plw, u, iters,
                                                              out);
  }
}

// Round 14
// 85.301 us; speedup vs baseline: 35.0271x; 35.0271x over previous
//
#include <hip/hip_runtime.h>

// LearnPermutations: K=256 independent 256x256 Sinkhorn normalizations.
// PROVEN BEST (R10, 82.9 us). One 1024-thread block per matrix; matrix
// register-resident (8x8/thread as packed float2). In-wave log2-domain row
// pass #1 (fused exp2) -> linear matrix with rowsums==1; then n_iters column
// epochs of scaling-vector Sinkhorn (epoch 1: u==1). Per epoch: ONE LDS
// round-trip with wave-combined partials (permlane32) + shallow 4-read
// quad-DPP tree, two barriers. Epilogue: out = a_ij * u_i * v_j.
//
// Structural notes from this session (negative results, do not retry):
//  - LDS atomicAdd colsums: 32-way same-address serialization, 3.9x slower (R9).
//  - Cross-block pair-split via L2/L3 handshake: coop-launch fragile, and
//    agent-scope polling causes cross-XCD coherence storms (R12/R13); even
//    ideal sync cost >= in-block barrier cost.
//  - Matrix (256KB) > LDS (160KB): register residency is forced.
//  - Early exit never fires at safe DELTA (R4).

#define KMAT 256

typedef float f2 __attribute__((ext_vector_type(2)));
typedef unsigned uint2_ev __attribute__((ext_vector_type(2)));

__device__ __forceinline__ float fast_exp2(float x) {
#if __has_builtin(__builtin_amdgcn_exp2f)
  return __builtin_amdgcn_exp2f(x);
#else
  return exp2f(x);
#endif
}

__device__ __forceinline__ float fast_log2(float x) {
#if __has_builtin(__builtin_amdgcn_logf)
  return __builtin_amdgcn_logf(x);
#else
  return __log2f(x);
#endif
}

__device__ __forceinline__ float fast_rcp(float x) {
#if __has_builtin(__builtin_amdgcn_rcpf)
  return __builtin_amdgcn_rcpf(x);
#else
  return 1.0f / x;
#endif
}

__device__ __forceinline__ f2 f2fma(f2 a, f2 b, f2 c) {
#if __has_builtin(__builtin_elementwise_fma)
  return __builtin_elementwise_fma(a, b, c);
#else
  f2 r; r[0] = fmaf(a[0], b[0], c[0]); r[1] = fmaf(a[1], b[1], c[1]); return r;
#endif
}

template <int CTRL>
__device__ __forceinline__ float dpp_movf(float x) {
  return __int_as_float(
      __builtin_amdgcn_update_dpp(0, __float_as_int(x), CTRL, 0xf, 0xf, true));
}

__device__ __forceinline__ uint2_ev pl16_swap(unsigned a, unsigned b) {
  return __builtin_amdgcn_permlane16_swap(a, b, false, false);
}

// 32-lane half-group reductions (verified construction, R1-R13).
__device__ __forceinline__ float hgroup_max(float x) {
  x = fmaxf(x, dpp_movf<0x121>(x));  // row_ror:1
  x = fmaxf(x, dpp_movf<0x122>(x));  // row_ror:2
  x = fmaxf(x, dpp_movf<0x124>(x));  // row_ror:4
  x = fmaxf(x, dpp_movf<0x128>(x));  // row_ror:8
  uint2_ev r = pl16_swap(__float_as_uint(x), __float_as_uint(x));
  return fmaxf(__uint_as_float(r[0]), __uint_as_float(r[1]));
}

__device__ __forceinline__ float hgroup_sum(float x) {
  x += dpp_movf<0x121>(x);
  x += dpp_movf<0x122>(x);
  x += dpp_movf<0x124>(x);
  x += dpp_movf<0x128>(x);
  uint2_ev r = pl16_swap(__float_as_uint(x), __float_as_uint(x));
  return __uint_as_float(r[0]) + __uint_as_float(r[1]);
}

// Combine lane l with lane l^32 (verified R1-R13 construction).
__device__ __forceinline__ float x32_sum(float x) {
#if __has_builtin(__builtin_amdgcn_permlane32_swap)
  uint2_ev r = __builtin_amdgcn_permlane32_swap(
      (unsigned)__float_as_int(x), (unsigned)__float_as_int(x), false, false);
  return __int_as_float((int)r[0]) + __int_as_float((int)r[1]);
#else
  return x + __shfl_xor(x, 32, 64);
#endif
}

// Gumbel noise + temperature scaling, output in log2 domain.
__device__ __forceinline__ float gumbel_la(float p, float uv, float scale) {
  float lnu = fast_log2(uv + 1e-20f) * 0.69314718056f;
  float g = fast_log2(1e-20f - lnu) * (-0.0069314718056f);
  return (p + g) * scale;
}

__global__ __launch_bounds__(1024)
__attribute__((amdgpu_waves_per_eu(4, 4)))
void lp_sinkhorn_kernel(
    const float* __restrict__ plw, const float* __restrict__ uin,
    const int* __restrict__ itp, float* __restrict__ out) {
  const int k = blockIdx.x;
  const int t = threadIdx.x;
  const int br = t >> 5;   // 0..31 : half-wave row-group (8 rows each)
  const int bc = t & 31;   // 0..31 : col-group (8 cols each)
  const int wv = t >> 6;   // wave 0..15
  const int lane = t & 63;

  // Wave partials: pw[w][32p+bc] (f2) = 16-row partial of column pair
  // (8bc+2p, 8bc+2p+1), rows 16w..16w+15. f2 stride 132 = 264 floats
  // (bank rotate 8/row) -> tree reads and writes are <=2-way (free).
  __shared__ f2 pw[16][132];
  __shared__ f2 colvp[132];        // rcp'd colsums, f2 slot 32p+bc
  float* pwF = (float*)pw;         // row stride = 264 floats
  float* colvF = (float*)colvp;    // scalar col slot s = 64p+2bc+h

  const int ts = t >> 2;   // tree: scalar col slot (0..255)
  const int tq = t & 3;    // tree: quad index (reads rows 4m+tq)

  // ---- schedule parameters from `iterations` (uniform) ----
  double frac = (double)itp[0] * 1e-5;
  frac = frac < 0.0 ? 0.0 : (frac > 1.0 ? 1.0 : frac);
  const int n_iters = (int)(20.0 + frac * 130.0);
  const float tauf = (float)exp2((-3.0 - 4.0 * frac) * 3.3219280948873623);
  const float scale = (float)(1.4426950408889634 / (double)tauf);

  f2 la[8][4];

  // ---- load + gumbel + scale (log2 domain) ----
  const float4* p4 = (const float4*)plw + k * 16384;
  const float4* u4 = (const float4*)uin + k * 16384;
#pragma unroll
  for (int i = 0; i < 8; ++i) {
    const int ridx = ((br << 3) + i) * 64 + (bc << 1);
    float4 p0 = p4[ridx];
    float4 p1 = p4[ridx + 1];
    float4 v0 = u4[ridx];
    float4 v1 = u4[ridx + 1];
    la[i][0] = f2{gumbel_la(p0.x, v0.x, scale), gumbel_la(p0.y, v0.y, scale)};
    la[i][1] = f2{gumbel_la(p0.z, v0.z, scale), gumbel_la(p0.w, v0.w, scale)};
    la[i][2] = f2{gumbel_la(p1.x, v1.x, scale), gumbel_la(p1.y, v1.y, scale)};
    la[i][3] = f2{gumbel_la(p1.z, v1.z, scale), gumbel_la(p1.w, v1.w, scale)};
  }

  // ---- row pass #1 (log domain, in-wave) fused convert to linear ----
  // After this, la is linear with rowsums == 1 (entries <= 1).
#pragma unroll
  for (int i = 0; i < 8; ++i) {
    float m = fmaxf(la[i][0][0], la[i][0][1]);
#pragma unroll
    for (int p = 1; p < 4; ++p) m = fmaxf(m, fmaxf(la[i][p][0], la[i][p][1]));
    m = hgroup_max(m);
    float s = 0.f;
#pragma unroll
    for (int p = 0; p < 4; ++p) {
      la[i][p] = f2{fast_exp2(la[i][p][0] - m), fast_exp2(la[i][p][1] - m)};
      s += la[i][p][0] + la[i][p][1];
    }
    s = hgroup_sum(s);
    const float r = fast_rcp(s);
#pragma unroll
    for (int p = 0; p < 4; ++p) la[i][p] *= f2{r, r};
  }

  float u[8] = {1.f, 1.f, 1.f, 1.f, 1.f, 1.f, 1.f, 1.f};

  // ---- epoch 1: col sums of row-normalized A (u == 1) ----
  {
    f2 cs[4];
#pragma unroll
    for (int p = 0; p < 4; ++p) cs[p] = la[0][p];
#pragma unroll
    for (int i = 1; i < 8; ++i)
#pragma unroll
      for (int p = 0; p < 4; ++p) cs[p] += la[i][p];
    // wave-combine (rows 16w..16w+15) and write from lanes < 32
#pragma unroll
    for (int p = 0; p < 4; ++p)
      cs[p] = f2{x32_sum(cs[p][0]), x32_sum(cs[p][1])};
    if (lane < 32) {
#pragma unroll
      for (int p = 0; p < 4; ++p) pw[wv][32 * p + bc] = cs[p];
    }
    __syncthreads();
    {  // shallow tree: 4 threads/col, 4 reads, quad-DPP finish
      float v = pwF[tq * 264 + ts];
#pragma unroll
      for (int m = 1; m < 4; ++m) v += pwF[(4 * m + tq) * 264 + ts];
      v += dpp_movf<0xB1>(v);  // quad xor1
      v += dpp_movf<0x4E>(v);  // quad xor2
      if (tq == 0) colvF[ts] = fast_rcp(v);
    }
    __syncthreads();
  }

  // ---- epochs 2..n: u = rcp(A v); col partials of a*u; tree -> v ----
  for (int it = 2; it <= n_iters; ++it) {
    f2 v2[4];
#pragma unroll
    for (int p = 0; p < 4; ++p) v2[p] = colvp[32 * p + bc];

    // phase A: row dots (packed) + in-wave reduce
#pragma unroll
    for (int i = 0; i < 8; ++i) {
      f2 a01 = la[i][0] * v2[0];
      a01 = f2fma(la[i][1], v2[1], a01);
      f2 a23 = la[i][2] * v2[2];
      a23 = f2fma(la[i][3], v2[3], a23);
      f2 acc = a01 + a23;
      u[i] = fast_rcp(hgroup_sum(acc[0] + acc[1]));
    }

    // phase B: col partials (packed fma) over this thread's 8 rows
    f2 cs[4];
    {
      const f2 ub0 = f2{u[0], u[0]};
#pragma unroll
      for (int p = 0; p < 4; ++p) cs[p] = la[0][p] * ub0;
    }
#pragma unroll
    for (int i = 1; i < 8; ++i) {
      const f2 ub = f2{u[i], u[i]};
#pragma unroll
      for (int p = 0; p < 4; ++p) cs[p] = f2fma(la[i][p], ub, cs[p]);
    }
    // wave-combine + write from lanes < 32
#pragma unroll
    for (int p = 0; p < 4; ++p)
      cs[p] = f2{x32_sum(cs[p][0]), x32_sum(cs[p][1])};
    if (lane < 32) {
#pragma unroll
      for (int p = 0; p < 4; ++p) pw[wv][32 * p + bc] = cs[p];
    }
    __syncthreads();

    {  // shallow tree -> colv = rcp(colsum)
      float v = pwF[tq * 264 + ts];
#pragma unroll
      for (int m = 1; m < 4; ++m) v += pwF[(4 * m + tq) * 264 + ts];
      v += dpp_movf<0xB1>(v);
      v += dpp_movf<0x4E>(v);
      if (tq == 0) colvF[ts] = fast_rcp(v);
    }
    __syncthreads();
  }

  // ---- epilogue: v = last colv; out = a_ij * u_i * v_j ----
  f2 v2[4];
#pragma unroll
  for (int p = 0; p < 4; ++p) v2[p] = colvp[32 * p + bc];

  float4* o4 = (float4*)out + k * 16384;
#pragma unroll
  for (int i = 0; i < 8; ++i) {
    const int ridx = ((br << 3) + i) * 64 + (bc << 1);
    const f2 ub = f2{u[i], u[i]};
    f2 r0 = (la[i][0] * ub) * v2[0];
    f2 r1 = (la[i][1] * ub) * v2[1];
    f2 r2 = (la[i][2] * ub) * v2[2];
    f2 r3 = (la[i][3] * ub) * v2[3];
    float4 a, b;
    a.x = r0[0]; a.y = r0[1]; a.z = r1[0]; a.w = r1[1];
    b.x = r2[0]; b.y = r2[1]; b.z = r3[0]; b.w = r3[1];
    o4[ridx] = a;
    o4[ridx + 1] = b;
  }
}

extern "C" void kernel_launch(void* const* d_in, const int* in_sizes, int n_in,
                              void* d_out, int out_size, void* d_ws,
                              size_t ws_size, hipStream_t stream) {
  const float* plw = (const float*)d_in[0];
  const float* u = (const float*)d_in[1];
  const int* iters = (const int*)d_in[2];
  float* out = (float*)d_out;
  (void)in_sizes; (void)n_in; (void)out_size; (void)d_ws; (void)ws_size;
  lp_sinkhorn_kernel<<<dim3(KMAT), dim3(1024), 0, stream>>>(plw, u, iters, out);
}